// Round 1
// baseline (1218.436 us; speedup 1.0000x reference)
//
#include <hip/hip_runtime.h>
#include <math.h>

#define BB 4
#define SS 1024
#define DD 1024
#define HH 16
#define DHH 64

// ---------------------------------------------------------------------------
// GEMM (NT): C[m][n] = sum_k A[m][k] * W[n][k]
// out_mode 0: C row-major [M][N]
// out_mode 1: n = h*DH+d, m = b*S+s  ->  C[((b*H+h)*S+s)*DH + d]   (B,H,S,DH)
// 64x64 tile, BK=16, 256 threads, 4x4 micro-tile per thread, fp32.
// ---------------------------------------------------------------------------
__global__ __launch_bounds__(256) void gemm_nt(
    const float* __restrict__ A, const float* __restrict__ W,
    float* __restrict__ C, int M, int N, int K, int out_mode)
{
    __shared__ __align__(16) float As[16][68];
    __shared__ __align__(16) float Bs[16][68];

    const int tid = threadIdx.x;
    const int tx = tid & 15, ty = tid >> 4;
    const int n0 = blockIdx.x * 64;
    const int m0 = blockIdx.y * 64;

    const int li = tid >> 2;         // 0..63 tile row
    const int lk = (tid & 3) * 4;    // 0,4,8,12

    float acc[4][4];
#pragma unroll
    for (int i = 0; i < 4; i++)
#pragma unroll
        for (int j = 0; j < 4; j++) acc[i][j] = 0.f;

    for (int k0 = 0; k0 < K; k0 += 16) {
        __syncthreads();
        float4 av = *(const float4*)&A[(size_t)(m0 + li) * K + k0 + lk];
        float4 bv = *(const float4*)&W[(size_t)(n0 + li) * K + k0 + lk];
        As[lk + 0][li] = av.x; As[lk + 1][li] = av.y;
        As[lk + 2][li] = av.z; As[lk + 3][li] = av.w;
        Bs[lk + 0][li] = bv.x; Bs[lk + 1][li] = bv.y;
        Bs[lk + 2][li] = bv.z; Bs[lk + 3][li] = bv.w;
        __syncthreads();
#pragma unroll
        for (int kk = 0; kk < 16; kk++) {
            float4 a = *(const float4*)&As[kk][ty * 4];
            float4 b = *(const float4*)&Bs[kk][tx * 4];
            float ar[4] = {a.x, a.y, a.z, a.w};
            float br[4] = {b.x, b.y, b.z, b.w};
#pragma unroll
            for (int i = 0; i < 4; i++)
#pragma unroll
                for (int j = 0; j < 4; j++)
                    acc[i][j] = fmaf(ar[i], br[j], acc[i][j]);
        }
    }

    if (out_mode == 1) {
        const int h = n0 >> 6;           // tile is 64 wide == one head
#pragma unroll
        for (int i = 0; i < 4; i++) {
            int m = m0 + ty * 4 + i;
            int b = m >> 10, s = m & 1023;
            float4 v = make_float4(acc[i][0], acc[i][1], acc[i][2], acc[i][3]);
            *(float4*)&C[(((size_t)(b * HH + h) * SS + s) * DHH) + tx * 4] = v;
        }
    } else {
#pragma unroll
        for (int i = 0; i < 4; i++) {
            float4 v = make_float4(acc[i][0], acc[i][1], acc[i][2], acc[i][3]);
            *(float4*)&C[(size_t)(m0 + ty * 4 + i) * N + n0 + tx * 4] = v;
        }
    }
}

// ---------------------------------------------------------------------------
// Fused relative attention, flash-style.
// Block = (i-tile of 64 q rows) x (b,h).  256 threads, 4x4 micro-tile.
// scores[i][j] = (q_i . k_j) * DH^-0.5 + [j<=i] (q_i . pe[S-1+j-i]) * DH^0.5
// masked -> -1e9; online softmax; O = softmax(scores) @ V
// pe band (127 rows) staged in LDS per j-tile; rows >= S zero-filled, which
// makes the j>i -> 0 condition automatic.
// ---------------------------------------------------------------------------
__global__ __launch_bounds__(256) void attn_kernel(
    const float* __restrict__ Q, const float* __restrict__ Kp,
    const float* __restrict__ V, const int* __restrict__ mask,
    const float* __restrict__ pe, float* __restrict__ Out)
{
    __shared__ __align__(16) float Qst[64][68];    // [d][r]
    __shared__ __align__(16) float Kst[64][68];    // [d][j], pre-scaled DH^-0.5
    __shared__ __align__(16) float Vs [64][68];    // [j][d]
    __shared__ __align__(16) float PEPt[64][132];  // phase1: PEt[d][o]; phase2: Pt[j][r]
    __shared__ float maski_s[64];
    __shared__ float maskj_s[64];

    const int tid = threadIdx.x;
    const int tx = tid & 15, ty = tid >> 4;
    const int ix = blockIdx.x;
    const int i0 = ix * 64;
    const int bh = blockIdx.y;
    const int b = bh / HH, h = bh % HH;

    const float sc_qk = 0.125f;   // DH^-0.5
    const float sc_pe = 8.0f;     // DH^0.5

    const float* Qbh = Q  + (size_t)bh * SS * DHH;
    const float* Kbh = Kp + (size_t)bh * SS * DHH;
    const float* Vbh = V  + (size_t)bh * SS * DHH;
    const float* peh = pe + (size_t)h * SS * DHH;

    // Q tile -> LDS transposed
    {
        int r = tid >> 2;
        int db = (tid & 3) * 16;
        const float* src = &Qbh[(size_t)(i0 + r) * DHH + db];
#pragma unroll
        for (int u = 0; u < 4; u++) {
            float4 v = *(const float4*)(src + 4 * u);
            Qst[db + 4 * u + 0][r] = v.x; Qst[db + 4 * u + 1][r] = v.y;
            Qst[db + 4 * u + 2][r] = v.z; Qst[db + 4 * u + 3][r] = v.w;
        }
        if (tid < 64) maski_s[tid] = (float)mask[b * SS + i0 + tid];
    }

    float m_run[4], l_run[4], O[4][4];
#pragma unroll
    for (int i = 0; i < 4; i++) {
        m_run[i] = -1e30f; l_run[i] = 0.f;
#pragma unroll
        for (int j = 0; j < 4; j++) O[i][j] = 0.f;
    }

    for (int jt = 0; jt < SS / 64; jt++) {
        const int j0 = jt * 64;
        __syncthreads();   // previous iteration's PV done

        // stage K (transposed, scaled), V, mask_j
        {
            int r = tid >> 2;
            int db = (tid & 3) * 16;
            const float* ksrc = &Kbh[(size_t)(j0 + r) * DHH + db];
            const float* vsrc = &Vbh[(size_t)(j0 + r) * DHH + db];
#pragma unroll
            for (int u = 0; u < 4; u++) {
                float4 kv = *(const float4*)(ksrc + 4 * u);
                Kst[db + 4 * u + 0][r] = kv.x * sc_qk;
                Kst[db + 4 * u + 1][r] = kv.y * sc_qk;
                Kst[db + 4 * u + 2][r] = kv.z * sc_qk;
                Kst[db + 4 * u + 3][r] = kv.w * sc_qk;
                float4 vv = *(const float4*)(vsrc + 4 * u);
                *(float4*)&Vs[r][db + 4 * u] = vv;
            }
            if (tid < 64) maskj_s[tid] = (float)mask[b * SS + j0 + tid];
        }

        const bool do_pe = (jt <= ix);
        if (do_pe) {
            // pe rows base..base+127 -> PEt[d][o] (transposed, scaled, OOB->0)
            const int base = SS - 1 + j0 - i0 - 63;
            const int o = tid >> 1;          // 0..127
            const int db = (tid & 1) * 32;
            const int g = base + o;
            if (g >= 0 && g < SS) {
                const float* psrc = &peh[(size_t)g * DHH + db];
#pragma unroll
                for (int u = 0; u < 8; u++) {
                    float4 v = *(const float4*)(psrc + 4 * u);
                    PEPt[db + 4 * u + 0][o] = v.x * sc_pe;
                    PEPt[db + 4 * u + 1][o] = v.y * sc_pe;
                    PEPt[db + 4 * u + 2][o] = v.z * sc_pe;
                    PEPt[db + 4 * u + 3][o] = v.w * sc_pe;
                }
            } else {
#pragma unroll
                for (int u = 0; u < 8; u++) {
                    PEPt[db + 4 * u + 0][o] = 0.f;
                    PEPt[db + 4 * u + 1][o] = 0.f;
                    PEPt[db + 4 * u + 2][o] = 0.f;
                    PEPt[db + 4 * u + 3][o] = 0.f;
                }
            }
        }
        __syncthreads();

        // ---- scores: qk
        float acc[4][4];
#pragma unroll
        for (int i = 0; i < 4; i++)
#pragma unroll
            for (int j = 0; j < 4; j++) acc[i][j] = 0.f;

#pragma unroll 16
        for (int d = 0; d < 64; d++) {
            float4 a = *(const float4*)&Qst[d][ty * 4];
            float4 bb = *(const float4*)&Kst[d][tx * 4];
            float ar[4] = {a.x, a.y, a.z, a.w};
            float br[4] = {bb.x, bb.y, bb.z, bb.w};
#pragma unroll
            for (int i = 0; i < 4; i++)
#pragma unroll
                for (int j = 0; j < 4; j++)
                    acc[i][j] = fmaf(ar[i], br[j], acc[i][j]);
        }

        // ---- scores: relative position term
        if (do_pe) {
            const int ot = 63 + 4 * (tx - ty);
#pragma unroll 4
            for (int d = 0; d < 64; d++) {
                float4 a = *(const float4*)&Qst[d][ty * 4];
                float ar[4] = {a.x, a.y, a.z, a.w};
                float pe7[7];
#pragma unroll
                for (int u = 0; u < 7; u++) pe7[u] = PEPt[d][ot - 3 + u];
#pragma unroll
                for (int i = 0; i < 4; i++)
#pragma unroll
                    for (int j = 0; j < 4; j++)
                        acc[i][j] = fmaf(ar[i], pe7[3 + j - i], acc[i][j]);
            }
        }

        // ---- mask + online softmax (rows replicated across the 16 tx lanes)
        float p[4][4];
        float alpha[4];
#pragma unroll
        for (int i = 0; i < 4; i++) {
            float mi = maski_s[ty * 4 + i];
            float rmax = -1e30f;
#pragma unroll
            for (int j = 0; j < 4; j++) {
                if (mi * maskj_s[tx * 4 + j] == 0.f) acc[i][j] = -1e9f;
                rmax = fmaxf(rmax, acc[i][j]);
            }
#pragma unroll
            for (int off = 1; off < 16; off <<= 1)
                rmax = fmaxf(rmax, __shfl_xor(rmax, off));
            float mnew = fmaxf(m_run[i], rmax);
            alpha[i] = __expf(m_run[i] - mnew);
            m_run[i] = mnew;
            float rsum = 0.f;
#pragma unroll
            for (int j = 0; j < 4; j++) {
                p[i][j] = __expf(acc[i][j] - mnew);
                rsum += p[i][j];
            }
#pragma unroll
            for (int off = 1; off < 16; off <<= 1)
                rsum += __shfl_xor(rsum, off);
            l_run[i] = l_run[i] * alpha[i] + rsum;
        }

        __syncthreads();   // everyone done reading PEt before Pt overwrites it

        // write P transposed: Pt[j][r]
#pragma unroll
        for (int i = 0; i < 4; i++)
#pragma unroll
            for (int j = 0; j < 4; j++)
                PEPt[tx * 4 + j][ty * 4 + i] = p[i][j];

        // rescale O
#pragma unroll
        for (int i = 0; i < 4; i++)
#pragma unroll
            for (int j = 0; j < 4; j++) O[i][j] *= alpha[i];

        __syncthreads();

        // ---- PV: O[r][d] += P[j][r] * V[j][d]
#pragma unroll 16
        for (int k = 0; k < 64; k++) {
            float4 pv = *(const float4*)&PEPt[k][ty * 4];
            float4 vv = *(const float4*)&Vs[k][tx * 4];
            float pr[4] = {pv.x, pv.y, pv.z, pv.w};
            float vr[4] = {vv.x, vv.y, vv.z, vv.w};
#pragma unroll
            for (int i = 0; i < 4; i++)
#pragma unroll
                for (int j = 0; j < 4; j++)
                    O[i][j] = fmaf(pr[i], vr[j], O[i][j]);
        }
    }

    // epilogue: normalize, write [B,S,D] (merges head transpose)
#pragma unroll
    for (int i = 0; i < 4; i++) {
        float inv = 1.f / l_run[i];
        float4 v = make_float4(O[i][0] * inv, O[i][1] * inv,
                               O[i][2] * inv, O[i][3] * inv);
        *(float4*)&Out[((size_t)b * SS + i0 + ty * 4 + i) * DD + h * DHH + tx * 4] = v;
    }
}

extern "C" void kernel_launch(void* const* d_in, const int* in_sizes, int n_in,
                              void* d_out, int out_size, void* d_ws, size_t ws_size,
                              hipStream_t stream)
{
    const float* query = (const float*)d_in[0];
    const float* key   = (const float*)d_in[1];
    const float* value = (const float*)d_in[2];
    const int*   mask  = (const int*)d_in[3];
    const float* pe    = (const float*)d_in[4];
    const float* Wq    = (const float*)d_in[5];
    const float* Wk    = (const float*)d_in[6];
    const float* Wv    = (const float*)d_in[7];
    const float* Wo    = (const float*)d_in[8];
    float* out = (float*)d_out;

    float* ws = (float*)d_ws;
    const size_t PROJ = (size_t)BB * HH * SS * DHH;   // 4,194,304 floats
    float* q_ws = ws;
    float* k_ws = ws + PROJ;
    float* v_ws = ws + 2 * PROJ;
    float* a_ws = ws + 3 * PROJ;

    dim3 gblk(256);
    dim3 ggrid(DD / 64, (BB * SS) / 64);   // (16, 64)

    gemm_nt<<<ggrid, gblk, 0, stream>>>(query, Wq, q_ws, BB * SS, DD, DD, 1);
    gemm_nt<<<ggrid, gblk, 0, stream>>>(key,   Wk, k_ws, BB * SS, DD, DD, 1);
    gemm_nt<<<ggrid, gblk, 0, stream>>>(value, Wv, v_ws, BB * SS, DD, DD, 1);

    attn_kernel<<<dim3(SS / 64, BB * HH), 256, 0, stream>>>(
        q_ws, k_ws, v_ws, mask, pe, a_ws);

    gemm_nt<<<ggrid, gblk, 0, stream>>>(a_ws, Wo, out, BB * SS, DD, DD, 0);
}

// Round 2
// 432.634 us; speedup vs baseline: 2.8163x; 2.8163x over previous
//
#include <hip/hip_runtime.h>
#include <math.h>

#define BB 4
#define SS 1024
#define DD 1024
#define HH 16
#define DHH 64

typedef _Float16 half8 __attribute__((ext_vector_type(8)));
typedef _Float16 half4v __attribute__((ext_vector_type(4)));
typedef float v4f __attribute__((ext_vector_type(4)));
typedef unsigned int u32;

// async global->LDS, 16B per lane. lds dest MUST be wave-base + lane*16.
__device__ __forceinline__ void gload_lds16(const void* g, void* l) {
    __builtin_amdgcn_global_load_lds(
        (const __attribute__((address_space(1))) u32*)(const u32*)g,
        (__attribute__((address_space(3))) u32*)(u32*)l, 16, 0, 0);
}

// ---------------------------------------------------------------------------
// convert: W_q, W_k(*0.125), W_v, W_o, pe(*8)  fp32 -> f16, contiguous in ws
// ---------------------------------------------------------------------------
__global__ __launch_bounds__(256) void convert_kernel(
    const float* __restrict__ wq, const float* __restrict__ wk,
    const float* __restrict__ wv, const float* __restrict__ wo,
    const float* __restrict__ pe, _Float16* __restrict__ dst)
{
    const int i4 = blockIdx.x * 256 + threadIdx.x;      // 0 .. 5M/4
    const int region = i4 >> 18;                        // 262144 float4 per 1M region
    const int local4 = i4 & 262143;
    const float* srcs[5] = {wq, wk, wv, wo, pe};
    const float scales[5] = {1.0f, 0.125f, 1.0f, 1.0f, 8.0f};
    const float sc = scales[region];
    float4 v = *(const float4*)(srcs[region] + (size_t)local4 * 4);
    half4v h = {(_Float16)(v.x * sc), (_Float16)(v.y * sc),
                (_Float16)(v.z * sc), (_Float16)(v.w * sc)};
    *(half4v*)(dst + ((size_t)region << 20) + (size_t)local4 * 4) = h;
}

// ---------------------------------------------------------------------------
// f16 MFMA GEMM: C = A (MxK) * W^T (W is NxK row-major), fp32 accumulate.
// 128x128 tile, BK=32, 256 threads = 4 waves (2x2 of 64x64), 16 MFMAs/iter/wave.
// A_F16=0: A is fp32 (convert during staging); A_F16=1: A is f16 (global_load_lds).
// C_MODE=0: fp32 row-major [M][N].  C_MODE=1: f16 [B,H,S,DH] relayout.
// ---------------------------------------------------------------------------
template<int A_F16, int C_MODE>
__global__ __launch_bounds__(256) void gemm_f16(
    const void* __restrict__ Ap, const _Float16* __restrict__ W,
    void* __restrict__ Cp, int M, int K)
{
    __shared__ _Float16 As[128 * 32];
    __shared__ _Float16 Bs[128 * 32];

    const int tid = threadIdx.x;
    const int n0 = blockIdx.x * 128;
    const int m0 = blockIdx.y * 128;
    const int w = tid >> 6, lane = tid & 63;
    const int lm = lane & 15, quad = lane >> 4;
    const int wr = w >> 1, wc = w & 1;

    v4f zero4 = {0.f, 0.f, 0.f, 0.f};
    v4f acc[4][4];
#pragma unroll
    for (int mi = 0; mi < 4; mi++)
#pragma unroll
        for (int ni = 0; ni < 4; ni++) acc[mi][ni] = zero4;

    for (int k0 = 0; k0 < K; k0 += 32) {
        __syncthreads();
        if (A_F16) {
            const _Float16* A = (const _Float16*)Ap;
#pragma unroll
            for (int u = 0; u < 2; u++) {
                int c = tid + 256 * u;
                int row = c >> 2, k8 = c & 3;
                gload_lds16(A + (size_t)(m0 + row) * K + k0 + k8 * 8, As + c * 8);
            }
        } else {
            const float* A = (const float*)Ap;
#pragma unroll
            for (int u = 0; u < 4; u++) {
                int c4 = tid + 256 * u;
                int row = c4 >> 3, k4 = c4 & 7;
                float4 v = *(const float4*)(A + (size_t)(m0 + row) * K + k0 + k4 * 4);
                half4v h = {(_Float16)v.x, (_Float16)v.y, (_Float16)v.z, (_Float16)v.w};
                *(half4v*)(As + row * 32 + k4 * 4) = h;
            }
        }
#pragma unroll
        for (int u = 0; u < 2; u++) {
            int c = tid + 256 * u;
            int row = c >> 2, k8 = c & 3;
            gload_lds16(W + (size_t)(n0 + row) * K + k0 + k8 * 8, Bs + c * 8);
        }
        __syncthreads();

        half8 af[4], bf[4];
#pragma unroll
        for (int mi = 0; mi < 4; mi++)
            af[mi] = *(const half8*)(As + (wr * 64 + mi * 16 + lm) * 32 + quad * 8);
#pragma unroll
        for (int ni = 0; ni < 4; ni++)
            bf[ni] = *(const half8*)(Bs + (wc * 64 + ni * 16 + lm) * 32 + quad * 8);
#pragma unroll
        for (int mi = 0; mi < 4; mi++)
#pragma unroll
            for (int ni = 0; ni < 4; ni++)
                acc[mi][ni] = __builtin_amdgcn_mfma_f32_16x16x32_f16(
                    af[mi], bf[ni], acc[mi][ni], 0, 0, 0);
    }

    // epilogue.  C/D layout: col = lane&15, row = quad*4 + reg.
    if (C_MODE == 1) {
        _Float16* C = (_Float16*)Cp;
        const int h = (n0 + wc * 64) >> 6;      // wave's 64 cols = one head
        const int d = lm;                        // + ni*16
#pragma unroll
        for (int mi = 0; mi < 4; mi++)
#pragma unroll
            for (int r = 0; r < 4; r++) {
                int m = m0 + wr * 64 + mi * 16 + quad * 4 + r;
                int b = m >> 10, s = m & 1023;
                size_t base = (((size_t)(b * HH + h) << 10) + s) * DHH;
#pragma unroll
                for (int ni = 0; ni < 4; ni++)
                    C[base + ni * 16 + d] = (_Float16)acc[mi][ni][r];
            }
    } else {
        float* C = (float*)Cp;
#pragma unroll
        for (int mi = 0; mi < 4; mi++)
#pragma unroll
            for (int r = 0; r < 4; r++) {
                size_t base = (size_t)(m0 + wr * 64 + mi * 16 + quad * 4 + r) * DD
                            + n0 + wc * 64 + lm;
#pragma unroll
                for (int ni = 0; ni < 4; ni++)
                    C[base + ni * 16] = acc[mi][ni][r];
            }
    }
}

// ---------------------------------------------------------------------------
// MFMA flash attention with relative-position band.
// Block: 64 q rows x (b,h); 4 waves, wave w owns q rows [w*16, w*16+16).
// scores = Q.K^T (K pre-scaled DH^-0.5) + band-gather(Q.PEband^T) (pe pre-scaled DH^0.5)
// PE band rows g0..g0+127, g0 = S-1+j0-i0-63; rows >= S zero-filled => j>i gives 0.
// Per-wave LDS scratch holds R (fp32 16x130) then overlaid P (f16 16x72).
// ---------------------------------------------------------------------------
__global__ __launch_bounds__(256) void attn_mfma(
    const _Float16* __restrict__ Qg, const _Float16* __restrict__ Kg,
    const _Float16* __restrict__ Vg, const int* __restrict__ mask,
    const _Float16* __restrict__ peg, _Float16* __restrict__ Og)
{
    __shared__ _Float16 Qs[64 * 64];        // 8 KB
    __shared__ _Float16 Ks[64 * 64];        // 8 KB
    __shared__ _Float16 Vt[64 * 72];        // 9 KB   [d][j], padded
    __shared__ _Float16 PEb[128 * 64];      // 16 KB  [o][d]
    __shared__ float    Rb[4][16 * 130];    // 33.3 KB, per-wave scratch (P overlays)

    const int tid = threadIdx.x;
    const int w = tid >> 6, lane = tid & 63;
    const int lm = lane & 15, quad = lane >> 4;
    const int it = blockIdx.x, i0 = it * 64;
    const int bh = blockIdx.y, b = bh >> 4, h = bh & 15;

    const _Float16* Qb = Qg + (size_t)bh * SS * DHH;
    const _Float16* Kb = Kg + (size_t)bh * SS * DHH;
    const _Float16* Vb = Vg + (size_t)bh * SS * DHH;
    const _Float16* peh = peg + (size_t)h * SS * DHH;

    // stage Q once: 64 rows x 64 f16 = 512 16B chunks
#pragma unroll
    for (int u = 0; u < 2; u++) {
        int c = tid + 256 * u;
        gload_lds16(Qb + (size_t)(i0 + (c >> 3)) * DHH + (c & 7) * 8, Qs + c * 8);
    }

    float mi_f[4];
#pragma unroll
    for (int r = 0; r < 4; r++)
        mi_f[r] = (float)mask[b * SS + i0 + w * 16 + quad * 4 + r];

    v4f zero4 = {0.f, 0.f, 0.f, 0.f};
    float m_run[4], l_run[4];
    v4f oacc[4];
#pragma unroll
    for (int r = 0; r < 4; r++) { m_run[r] = -1e30f; l_run[r] = 0.f; }
#pragma unroll
    for (int nb = 0; nb < 4; nb++) oacc[nb] = zero4;

    for (int jt = 0; jt < SS / 64; jt++) {
        const int j0 = jt * 64;
        const bool do_pe = (jt <= it);
        __syncthreads();                                   // (a) prev-iter LDS reads done

        // stage K
#pragma unroll
        for (int u = 0; u < 2; u++) {
            int c = tid + 256 * u;
            gload_lds16(Kb + (size_t)(j0 + (c >> 3)) * DHH + (c & 7) * 8, Ks + c * 8);
        }
        // stage V transposed
#pragma unroll
        for (int u = 0; u < 2; u++) {
            int c = tid + 256 * u;
            int row = c >> 3, k8 = c & 7;
            half8 v = *(const half8*)(Vb + (size_t)(j0 + row) * DHH + k8 * 8);
#pragma unroll
            for (int e = 0; e < 8; e++) Vt[(k8 * 8 + e) * 72 + row] = v[e];
        }
        // stage PE band (128 rows x 64)
        if (do_pe) {
            const int g0 = SS - 1 + j0 - i0 - 63;          // in [0, 960]
#pragma unroll
            for (int u = 0; u < 4; u++) {
                int c = tid + 256 * u;
                int o = c >> 3, k8 = c & 7;
                int g = g0 + o;
                half8 v = {0, 0, 0, 0, 0, 0, 0, 0};
                if (g < SS) v = *(const half8*)(peh + (size_t)g * DHH + k8 * 8);
                *(half8*)(PEb + o * 64 + k8 * 8) = v;
            }
        }
        float mj_f[4];
#pragma unroll
        for (int nb = 0; nb < 4; nb++)
            mj_f[nb] = (float)mask[b * SS + j0 + nb * 16 + lm];
        __syncthreads();                                   // (b) staging visible

        // ---- QK^T
        half8 qf[2];
#pragma unroll
        for (int kc = 0; kc < 2; kc++)
            qf[kc] = *(const half8*)(Qs + (w * 16 + lm) * 64 + kc * 32 + quad * 8);
        v4f sacc[4];
#pragma unroll
        for (int nb = 0; nb < 4; nb++) sacc[nb] = zero4;
#pragma unroll
        for (int nb = 0; nb < 4; nb++)
#pragma unroll
            for (int kc = 0; kc < 2; kc++) {
                half8 kf = *(const half8*)(Ks + (nb * 16 + lm) * 64 + kc * 32 + quad * 8);
                sacc[nb] = __builtin_amdgcn_mfma_f32_16x16x32_f16(qf[kc], kf, sacc[nb], 0, 0, 0);
            }

        // ---- relative position band
        if (do_pe) {
            v4f racc[8];
#pragma unroll
            for (int cb = 0; cb < 8; cb++) racc[cb] = zero4;
#pragma unroll
            for (int cb = 0; cb < 8; cb++)
#pragma unroll
                for (int kc = 0; kc < 2; kc++) {
                    half8 pf = *(const half8*)(PEb + (cb * 16 + lm) * 64 + kc * 32 + quad * 8);
                    racc[cb] = __builtin_amdgcn_mfma_f32_16x16x32_f16(qf[kc], pf, racc[cb], 0, 0, 0);
                }
            float* Rw = &Rb[w][0];
#pragma unroll
            for (int cb = 0; cb < 8; cb++)
#pragma unroll
                for (int r = 0; r < 4; r++)
                    Rw[(quad * 4 + r) * 130 + cb * 16 + lm] = racc[cb][r];
            __syncthreads();                               // (c) Rb visible
            // gather diagonal: c = jc - i_rel + 63
#pragma unroll
            for (int nb = 0; nb < 4; nb++)
#pragma unroll
                for (int r = 0; r < 4; r++) {
                    int c = nb * 16 + lm - (w * 16 + quad * 4 + r) + 63;
                    sacc[nb][r] += Rw[(quad * 4 + r) * 130 + c];
                }
            __syncthreads();                               // (d) gather done before P overlay
        }

        // ---- mask + online softmax
        float p[4][4], alpha[4];
#pragma unroll
        for (int r = 0; r < 4; r++) {
            float rmax = -1e30f;
#pragma unroll
            for (int nb = 0; nb < 4; nb++) {
                float s = sacc[nb][r];
                if (mi_f[r] * mj_f[nb] == 0.f) s = -1e9f;
                sacc[nb][r] = s;
                rmax = fmaxf(rmax, s);
            }
#pragma unroll
            for (int off = 1; off < 16; off <<= 1)
                rmax = fmaxf(rmax, __shfl_xor(rmax, off));
            float mnew = fmaxf(m_run[r], rmax);
            alpha[r] = __expf(m_run[r] - mnew);
            m_run[r] = mnew;
            float rsum = 0.f;
#pragma unroll
            for (int nb = 0; nb < 4; nb++) {
                p[nb][r] = __expf(sacc[nb][r] - mnew);
                rsum += p[nb][r];
            }
#pragma unroll
            for (int off = 1; off < 16; off <<= 1)
                rsum += __shfl_xor(rsum, off);
            l_run[r] = l_run[r] * alpha[r] + rsum;
        }

        // write P (f16) into per-wave overlay; rescale O
        _Float16* Pw = (_Float16*)&Rb[w][0];
#pragma unroll
        for (int nb = 0; nb < 4; nb++)
#pragma unroll
            for (int r = 0; r < 4; r++)
                Pw[(quad * 4 + r) * 72 + nb * 16 + lm] = (_Float16)p[nb][r];
#pragma unroll
        for (int nb = 0; nb < 4; nb++)
#pragma unroll
            for (int r = 0; r < 4; r++) oacc[nb][r] *= alpha[r];
        __syncthreads();                                   // (e) P visible

        // ---- PV
#pragma unroll
        for (int kc = 0; kc < 2; kc++) {
            half8 pfrag = *(const half8*)(Pw + lm * 72 + kc * 32 + quad * 8);
#pragma unroll
            for (int nb = 0; nb < 4; nb++) {
                half8 vfrag = *(const half8*)(Vt + (nb * 16 + lm) * 72 + kc * 32 + quad * 8);
                oacc[nb] = __builtin_amdgcn_mfma_f32_16x16x32_f16(pfrag, vfrag, oacc[nb], 0, 0, 0);
            }
        }
    }

    // epilogue: normalize, write f16 [B,S,D]
#pragma unroll
    for (int r = 0; r < 4; r++) {
        float inv = 1.f / l_run[r];
        int s = i0 + w * 16 + quad * 4 + r;
#pragma unroll
        for (int nb = 0; nb < 4; nb++)
            Og[((size_t)b * SS + s) * DD + h * DHH + nb * 16 + lm] =
                (_Float16)(oacc[nb][r] * inv);
    }
}

extern "C" void kernel_launch(void* const* d_in, const int* in_sizes, int n_in,
                              void* d_out, int out_size, void* d_ws, size_t ws_size,
                              hipStream_t stream)
{
    const float* query = (const float*)d_in[0];
    const float* key   = (const float*)d_in[1];
    const float* value = (const float*)d_in[2];
    const int*   mask  = (const int*)d_in[3];
    const float* pe    = (const float*)d_in[4];
    const float* Wq    = (const float*)d_in[5];
    const float* Wk    = (const float*)d_in[6];
    const float* Wv    = (const float*)d_in[7];
    const float* Wo    = (const float*)d_in[8];
    float* out = (float*)d_out;

    _Float16* ws16 = (_Float16*)d_ws;
    const size_t MEG = 1048576;
    _Float16* wqf = ws16;
    _Float16* wkf = ws16 + 1 * MEG;
    _Float16* wvf = ws16 + 2 * MEG;
    _Float16* wof = ws16 + 3 * MEG;
    _Float16* pef = ws16 + 4 * MEG;
    _Float16* qp  = ws16 + 5 * MEG;     // [B,H,S,DH] 4M each
    _Float16* kp  = ws16 + 9 * MEG;
    _Float16* vp  = ws16 + 13 * MEG;
    _Float16* ao  = ws16 + 17 * MEG;    // [B,S,D]

    convert_kernel<<<5120, 256, 0, stream>>>(Wq, Wk, Wv, Wo, pe, ws16);

    dim3 ggrid(DD / 128, (BB * SS) / 128);   // (8, 32)
    gemm_f16<0, 1><<<ggrid, 256, 0, stream>>>(query, wqf, qp, BB * SS, DD);
    gemm_f16<0, 1><<<ggrid, 256, 0, stream>>>(key,   wkf, kp, BB * SS, DD);
    gemm_f16<0, 1><<<ggrid, 256, 0, stream>>>(value, wvf, vp, BB * SS, DD);

    attn_mfma<<<dim3(SS / 64, BB * HH), 256, 0, stream>>>(qp, kp, vp, mask, pef, ao);

    gemm_f16<1, 0><<<ggrid, 256, 0, stream>>>(ao, wof, out, BB * SS, DD);
}

// Round 5
// 370.495 us; speedup vs baseline: 3.2887x; 1.1677x over previous
//
#include <hip/hip_runtime.h>
#include <math.h>

#define BB 4
#define SS 1024
#define DD 1024
#define HH 16
#define DHH 64

typedef _Float16 half8 __attribute__((ext_vector_type(8)));
typedef _Float16 half4v __attribute__((ext_vector_type(4)));
typedef float v4f __attribute__((ext_vector_type(4)));
typedef unsigned int u32;
typedef unsigned short u16;

// async global->LDS, 16B/lane. LDS dest is wave-uniform base + lane*16.
__device__ __forceinline__ void gload_lds16(const void* g, void* l) {
    __builtin_amdgcn_global_load_lds(
        (const __attribute__((address_space(1))) u32*)(const u32*)g,
        (__attribute__((address_space(3))) u32*)(u32*)l, 16, 0, 0);
}

// ---------------------------------------------------------------------------
// convert: W_q, W_k(*0.125), W_v, W_o, pe(*8)  fp32 -> f16  (R2-verified)
// ---------------------------------------------------------------------------
__global__ __launch_bounds__(256) void convert_kernel(
    const float* __restrict__ wq, const float* __restrict__ wk,
    const float* __restrict__ wv, const float* __restrict__ wo,
    const float* __restrict__ pe, _Float16* __restrict__ dst)
{
    const int i4 = blockIdx.x * 256 + threadIdx.x;
    const int region = i4 >> 18;
    const int local4 = i4 & 262143;
    const float* srcs[5] = {wq, wk, wv, wo, pe};
    const float scales[5] = {1.0f, 0.125f, 1.0f, 1.0f, 8.0f};
    const float sc = scales[region];
    float4 v = *(const float4*)(srcs[region] + (size_t)local4 * 4);
    half4v h = {(_Float16)(v.x * sc), (_Float16)(v.y * sc),
                (_Float16)(v.z * sc), (_Float16)(v.w * sc)};
    *(half4v*)(dst + ((size_t)region << 20) + (size_t)local4 * 4) = h;
}

// ---------------------------------------------------------------------------
// Fused Q/K/V projection GEMMs (z = 0,1,2): C = A(4096x1024 fp32) * W^T,
// 128x64 tile, BK=32, 4 waves (each 32m x 64n), XOR-swizzled LDS.  [SUSPECT]
// Output f16 [B,H,S,DH].
// ---------------------------------------------------------------------------
__global__ __launch_bounds__(256) void gemm_proj(
    const float* __restrict__ Aq, const float* __restrict__ Ak,
    const float* __restrict__ Av,
    const _Float16* __restrict__ Wqf, const _Float16* __restrict__ Wkf,
    const _Float16* __restrict__ Wvf,
    _Float16* __restrict__ Cq, _Float16* __restrict__ Ck,
    _Float16* __restrict__ Cv)
{
    __shared__ _Float16 As[128 * 32];
    __shared__ _Float16 Bs[64 * 32];

    const int z = blockIdx.z;
    const float* A = z == 0 ? Aq : z == 1 ? Ak : Av;
    const _Float16* W = z == 0 ? Wqf : z == 1 ? Wkf : Wvf;
    _Float16* C = z == 0 ? Cq : z == 1 ? Ck : Cv;

    const int tid = threadIdx.x;
    const int w = tid >> 6, lane = tid & 63, lm = lane & 15, quad = lane >> 4;
    const int n0 = blockIdx.x * 64, m0 = blockIdx.y * 128;

    const int brow = tid >> 2, blc = (tid & 3) ^ (brow & 3);

    v4f zero4 = {0.f, 0.f, 0.f, 0.f};
    v4f acc[2][4];
#pragma unroll
    for (int mi = 0; mi < 2; mi++)
#pragma unroll
        for (int ni = 0; ni < 4; ni++) acc[mi][ni] = zero4;

    for (int k0 = 0; k0 < DD; k0 += 32) {
        __syncthreads();
        gload_lds16(W + (size_t)(n0 + brow) * DD + k0 + blc * 8, Bs + tid * 8);
#pragma unroll
        for (int u = 0; u < 4; u++) {
            int c4 = tid + 256 * u;
            int row = c4 >> 3, k4 = c4 & 7;
            float4 v = *(const float4*)(A + (size_t)(m0 + row) * DD + k0 + k4 * 4);
            half4v hv = {(_Float16)v.x, (_Float16)v.y, (_Float16)v.z, (_Float16)v.w};
            int c16 = k4 >> 1, hlf = k4 & 1;
            *(half4v*)(As + row * 32 + (((c16 ^ (row & 3)) << 3) + (hlf << 2))) = hv;
        }
        __syncthreads();

        half8 af[2], bf[4];
#pragma unroll
        for (int mi = 0; mi < 2; mi++) {
            int row = w * 32 + mi * 16 + lm;
            af[mi] = *(const half8*)(As + row * 32 + ((quad ^ (row & 3)) << 3));
        }
#pragma unroll
        for (int ni = 0; ni < 4; ni++) {
            int row = ni * 16 + lm;
            bf[ni] = *(const half8*)(Bs + row * 32 + ((quad ^ (row & 3)) << 3));
        }
#pragma unroll
        for (int mi = 0; mi < 2; mi++)
#pragma unroll
            for (int ni = 0; ni < 4; ni++)
                acc[mi][ni] = __builtin_amdgcn_mfma_f32_16x16x32_f16(
                    af[mi], bf[ni], acc[mi][ni], 0, 0, 0);
    }

    const int h = n0 >> 6;
#pragma unroll
    for (int mi = 0; mi < 2; mi++)
#pragma unroll
        for (int r = 0; r < 4; r++) {
            int m = m0 + w * 32 + mi * 16 + quad * 4 + r;
            int b = m >> 10, s = m & 1023;
            size_t base = ((size_t)(b * HH + h) * SS + s) * DHH;
#pragma unroll
            for (int ni = 0; ni < 4; ni++)
                C[base + ni * 16 + lm] = (_Float16)acc[mi][ni][r];
        }
}

// ---------------------------------------------------------------------------
// Output GEMM: C(fp32 4096x1024) = A(f16) * W^T.  [SUSPECT]
// ---------------------------------------------------------------------------
__global__ __launch_bounds__(256) void gemm_out(
    const _Float16* __restrict__ A, const _Float16* __restrict__ W,
    float* __restrict__ C)
{
    __shared__ _Float16 As[128 * 32];
    __shared__ _Float16 Bs[64 * 32];

    const int tid = threadIdx.x;
    const int w = tid >> 6, lane = tid & 63, lm = lane & 15, quad = lane >> 4;
    const int n0 = blockIdx.x * 64, m0 = blockIdx.y * 128;
    const int brow = tid >> 2, blc = (tid & 3) ^ (brow & 3);

    v4f zero4 = {0.f, 0.f, 0.f, 0.f};
    v4f acc[2][4];
#pragma unroll
    for (int mi = 0; mi < 2; mi++)
#pragma unroll
        for (int ni = 0; ni < 4; ni++) acc[mi][ni] = zero4;

    for (int k0 = 0; k0 < DD; k0 += 32) {
        __syncthreads();
        gload_lds16(W + (size_t)(n0 + brow) * DD + k0 + blc * 8, Bs + tid * 8);
#pragma unroll
        for (int u = 0; u < 2; u++) {
            int p = tid + 256 * u;
            int row = p >> 2, lc = (p & 3) ^ (row & 3);
            gload_lds16(A + (size_t)(m0 + row) * DD + k0 + lc * 8, As + p * 8);
        }
        __syncthreads();

        half8 af[2], bf[4];
#pragma unroll
        for (int mi = 0; mi < 2; mi++) {
            int row = w * 32 + mi * 16 + lm;
            af[mi] = *(const half8*)(As + row * 32 + ((quad ^ (row & 3)) << 3));
        }
#pragma unroll
        for (int ni = 0; ni < 4; ni++) {
            int row = ni * 16 + lm;
            bf[ni] = *(const half8*)(Bs + row * 32 + ((quad ^ (row & 3)) << 3));
        }
#pragma unroll
        for (int mi = 0; mi < 2; mi++)
#pragma unroll
            for (int ni = 0; ni < 4; ni++)
                acc[mi][ni] = __builtin_amdgcn_mfma_f32_16x16x32_f16(
                    af[mi], bf[ni], acc[mi][ni], 0, 0, 0);
    }

#pragma unroll
    for (int mi = 0; mi < 2; mi++)
#pragma unroll
        for (int r = 0; r < 4; r++) {
            size_t base = (size_t)(m0 + w * 32 + mi * 16 + quad * 4 + r) * DD
                        + n0 + lm;
#pragma unroll
            for (int ni = 0; ni < 4; ni++)
                C[base + ni * 16] = acc[mi][ni][r];
        }
}

// ---------------------------------------------------------------------------
// MFMA flash attention — R2 kernel VERBATIM (verified: absmax 0.0156).
// Block: 64 q rows x (b,h); 4 waves; per-wave R scratch + barriers.
// ---------------------------------------------------------------------------
__global__ __launch_bounds__(256) void attn_mfma(
    const _Float16* __restrict__ Qg, const _Float16* __restrict__ Kg,
    const _Float16* __restrict__ Vg, const int* __restrict__ mask,
    const _Float16* __restrict__ peg, _Float16* __restrict__ Og)
{
    __shared__ _Float16 Qs[64 * 64];        // 8 KB
    __shared__ _Float16 Ks[64 * 64];        // 8 KB
    __shared__ _Float16 Vt[64 * 72];        // 9 KB   [d][j], padded
    __shared__ _Float16 PEb[128 * 64];      // 16 KB  [o][d]
    __shared__ float    Rb[4][16 * 130];    // 33.3 KB, per-wave scratch (P overlays)

    const int tid = threadIdx.x;
    const int w = tid >> 6, lane = tid & 63;
    const int lm = lane & 15, quad = lane >> 4;
    const int it = blockIdx.x, i0 = it * 64;
    const int bh = blockIdx.y, b = bh >> 4, h = bh & 15;

    const _Float16* Qb = Qg + (size_t)bh * SS * DHH;
    const _Float16* Kb = Kg + (size_t)bh * SS * DHH;
    const _Float16* Vb = Vg + (size_t)bh * SS * DHH;
    const _Float16* peh = peg + (size_t)h * SS * DHH;

    // stage Q once: 64 rows x 64 f16 = 512 16B chunks
#pragma unroll
    for (int u = 0; u < 2; u++) {
        int c = tid + 256 * u;
        gload_lds16(Qb + (size_t)(i0 + (c >> 3)) * DHH + (c & 7) * 8, Qs + c * 8);
    }

    float mi_f[4];
#pragma unroll
    for (int r = 0; r < 4; r++)
        mi_f[r] = (float)mask[b * SS + i0 + w * 16 + quad * 4 + r];

    v4f zero4 = {0.f, 0.f, 0.f, 0.f};
    float m_run[4], l_run[4];
    v4f oacc[4];
#pragma unroll
    for (int r = 0; r < 4; r++) { m_run[r] = -1e30f; l_run[r] = 0.f; }
#pragma unroll
    for (int nb = 0; nb < 4; nb++) oacc[nb] = zero4;

    for (int jt = 0; jt < SS / 64; jt++) {
        const int j0 = jt * 64;
        const bool do_pe = (jt <= it);
        __syncthreads();                                   // (a) prev-iter LDS reads done

        // stage K
#pragma unroll
        for (int u = 0; u < 2; u++) {
            int c = tid + 256 * u;
            gload_lds16(Kb + (size_t)(j0 + (c >> 3)) * DHH + (c & 7) * 8, Ks + c * 8);
        }
        // stage V transposed
#pragma unroll
        for (int u = 0; u < 2; u++) {
            int c = tid + 256 * u;
            int row = c >> 3, k8 = c & 7;
            half8 v = *(const half8*)(Vb + (size_t)(j0 + row) * DHH + k8 * 8);
#pragma unroll
            for (int e = 0; e < 8; e++) Vt[(k8 * 8 + e) * 72 + row] = v[e];
        }
        // stage PE band (128 rows x 64)
        if (do_pe) {
            const int g0 = SS - 1 + j0 - i0 - 63;          // in [0, 960]
#pragma unroll
            for (int u = 0; u < 4; u++) {
                int c = tid + 256 * u;
                int o = c >> 3, k8 = c & 7;
                int g = g0 + o;
                half8 v = {0, 0, 0, 0, 0, 0, 0, 0};
                if (g < SS) v = *(const half8*)(peh + (size_t)g * DHH + k8 * 8);
                *(half8*)(PEb + o * 64 + k8 * 8) = v;
            }
        }
        float mj_f[4];
#pragma unroll
        for (int nb = 0; nb < 4; nb++)
            mj_f[nb] = (float)mask[b * SS + j0 + nb * 16 + lm];
        __syncthreads();                                   // (b) staging visible

        // ---- QK^T
        half8 qf[2];
#pragma unroll
        for (int kc = 0; kc < 2; kc++)
            qf[kc] = *(const half8*)(Qs + (w * 16 + lm) * 64 + kc * 32 + quad * 8);
        v4f sacc[4];
#pragma unroll
        for (int nb = 0; nb < 4; nb++) sacc[nb] = zero4;
#pragma unroll
        for (int nb = 0; nb < 4; nb++)
#pragma unroll
            for (int kc = 0; kc < 2; kc++) {
                half8 kf = *(const half8*)(Ks + (nb * 16 + lm) * 64 + kc * 32 + quad * 8);
                sacc[nb] = __builtin_amdgcn_mfma_f32_16x16x32_f16(qf[kc], kf, sacc[nb], 0, 0, 0);
            }

        // ---- relative position band
        if (do_pe) {
            v4f racc[8];
#pragma unroll
            for (int cb = 0; cb < 8; cb++) racc[cb] = zero4;
#pragma unroll
            for (int cb = 0; cb < 8; cb++)
#pragma unroll
                for (int kc = 0; kc < 2; kc++) {
                    half8 pf = *(const half8*)(PEb + (cb * 16 + lm) * 64 + kc * 32 + quad * 8);
                    racc[cb] = __builtin_amdgcn_mfma_f32_16x16x32_f16(qf[kc], pf, racc[cb], 0, 0, 0);
                }
            float* Rw = &Rb[w][0];
#pragma unroll
            for (int cb = 0; cb < 8; cb++)
#pragma unroll
                for (int r = 0; r < 4; r++)
                    Rw[(quad * 4 + r) * 130 + cb * 16 + lm] = racc[cb][r];
            __syncthreads();                               // (c) Rb visible
            // gather diagonal: c = jc - i_rel + 63
#pragma unroll
            for (int nb = 0; nb < 4; nb++)
#pragma unroll
                for (int r = 0; r < 4; r++) {
                    int c = nb * 16 + lm - (w * 16 + quad * 4 + r) + 63;
                    sacc[nb][r] += Rw[(quad * 4 + r) * 130 + c];
                }
            __syncthreads();                               // (d) gather done before P overlay
        }

        // ---- mask + online softmax
        float p[4][4];
        float alpha[4];
#pragma unroll
        for (int i = 0; i < 4; i++) {
            float mi = mi_f[i];
            float rmax = -1e30f;
#pragma unroll
            for (int j = 0; j < 4; j++) {
                float s = sacc[j][i];
                if (mi * mj_f[j] == 0.f) s = -1e9f;
                sacc[j][i] = s;
                rmax = fmaxf(rmax, s);
            }
#pragma unroll
            for (int off = 1; off < 16; off <<= 1)
                rmax = fmaxf(rmax, __shfl_xor(rmax, off));
            float mnew = fmaxf(m_run[i], rmax);
            alpha[i] = __expf(m_run[i] - mnew);
            m_run[i] = mnew;
            float rsum = 0.f;
#pragma unroll
            for (int j = 0; j < 4; j++) {
                p[j][i] = __expf(sacc[j][i] - mnew);
                rsum += p[j][i];
            }
#pragma unroll
            for (int off = 1; off < 16; off <<= 1)
                rsum += __shfl_xor(rsum, off);
            l_run[i] = l_run[i] * alpha[i] + rsum;
        }

        // write P (f16) into per-wave overlay; rescale O
        _Float16* Pw = (_Float16*)&Rb[w][0];
#pragma unroll
        for (int nb = 0; nb < 4; nb++)
#pragma unroll
            for (int r = 0; r < 4; r++)
                Pw[(quad * 4 + r) * 72 + nb * 16 + lm] = (_Float16)p[nb][r];
#pragma unroll
        for (int nb = 0; nb < 4; nb++)
#pragma unroll
            for (int r = 0; r < 4; r++) oacc[nb][r] *= alpha[r];
        __syncthreads();                                   // (e) P visible

        // ---- PV
#pragma unroll
        for (int kc = 0; kc < 2; kc++) {
            half8 pfrag = *(const half8*)(Pw + lm * 72 + kc * 32 + quad * 8);
#pragma unroll
            for (int nb = 0; nb < 4; nb++) {
                half8 vfrag = *(const half8*)(Vt + (nb * 16 + lm) * 72 + kc * 32 + quad * 8);
                oacc[nb] = __builtin_amdgcn_mfma_f32_16x16x32_f16(pfrag, vfrag, oacc[nb], 0, 0, 0);
            }
        }
    }

    // epilogue: normalize, write f16 [B,S,D]
#pragma unroll
    for (int r = 0; r < 4; r++) {
        float inv = 1.f / l_run[r];
        int s = i0 + w * 16 + quad * 4 + r;
#pragma unroll
        for (int nb = 0; nb < 4; nb++)
            Og[((size_t)b * SS + s) * DD + h * DHH + nb * 16 + lm] =
                (_Float16)(oacc[nb][r] * inv);
    }
}

extern "C" void kernel_launch(void* const* d_in, const int* in_sizes, int n_in,
                              void* d_out, int out_size, void* d_ws, size_t ws_size,
                              hipStream_t stream)
{
    const float* query = (const float*)d_in[0];
    const float* key   = (const float*)d_in[1];
    const float* value = (const float*)d_in[2];
    const int*   mask  = (const int*)d_in[3];
    const float* pe    = (const float*)d_in[4];
    const float* Wq    = (const float*)d_in[5];
    const float* Wk    = (const float*)d_in[6];
    const float* Wv    = (const float*)d_in[7];
    const float* Wo    = (const float*)d_in[8];
    float* out = (float*)d_out;

    _Float16* ws16 = (_Float16*)d_ws;
    const size_t MEG = 1048576;
    _Float16* wqf = ws16;
    _Float16* wkf = ws16 + 1 * MEG;
    _Float16* wvf = ws16 + 2 * MEG;
    _Float16* wof = ws16 + 3 * MEG;
    _Float16* pef = ws16 + 4 * MEG;
    _Float16* qp  = ws16 + 5 * MEG;     // [B,H,S,DH]
    _Float16* kp  = ws16 + 9 * MEG;     // [B,H,S,DH]
    _Float16* vp  = ws16 + 13 * MEG;    // [B,H,S,DH]
    _Float16* ao  = ws16 + 17 * MEG;    // [B,S,D]

    convert_kernel<<<5120, 256, 0, stream>>>(Wq, Wk, Wv, Wo, pe, ws16);

    gemm_proj<<<dim3(DD / 64, (BB * SS) / 128, 3), 256, 0, stream>>>(
        query, key, value, wqf, wkf, wvf, qp, kp, vp);

    attn_mfma<<<dim3(SS / 64, BB * HH), 256, 0, stream>>>(qp, kp, vp, mask, pef, ao);

    gemm_out<<<dim3(DD / 64, (BB * SS) / 128), 256, 0, stream>>>(ao, wof, out);
}